// Round 5
// baseline (127.621 us; speedup 1.0000x reference)
//
#include <hip/hip_runtime.h>

#define NQ 11
#define NL 3
#define S  2048
#define NB 8
#define NA 96
#define NF 64
#define PADW 100

typedef float v2f __attribute__((ext_vector_type(2)));

__device__ __forceinline__ float sigmoidf_(float x) { return 1.0f / (1.0f + expf(-x)); }

__device__ __forceinline__ float rl_(float v, int srclane) {
    return __builtin_bit_cast(float, __builtin_amdgcn_readlane(__builtin_bit_cast(int, v), srclane));
}

// lane-xor shuffle: DPP for masks 1,2,8; ds_swizzle for 4,16; shfl for 32 (verified r4)
template<int M> __device__ __forceinline__ float sxf(float x) {
    if constexpr (M == 1)
        return __builtin_bit_cast(float, __builtin_amdgcn_mov_dpp(__builtin_bit_cast(int, x), 0xB1, 0xF, 0xF, true));
    else if constexpr (M == 2)
        return __builtin_bit_cast(float, __builtin_amdgcn_mov_dpp(__builtin_bit_cast(int, x), 0x4E, 0xF, 0xF, true));
    else if constexpr (M == 8)
        return __builtin_bit_cast(float, __builtin_amdgcn_mov_dpp(__builtin_bit_cast(int, x), 0x128, 0xF, 0xF, true));
    else if constexpr (M == 4)
        return __builtin_bit_cast(float, __builtin_amdgcn_ds_swizzle(__builtin_bit_cast(int, x), 0x101F));
    else if constexpr (M == 16)
        return __builtin_bit_cast(float, __builtin_amdgcn_ds_swizzle(__builtin_bit_cast(int, x), 0x401F));
    else
        return __shfl_xor(x, 32, 64);
}
template<int M> __device__ __forceinline__ v2f sxv(v2f w) {
    v2f r; r.x = sxf<M>(w.x); r.y = sxf<M>(w.y); return r;
}

// ---- gate primitives; statevector w[4] (v2f): s = lane | wv<<6 | comp<<8 | t<<9 ----
template<int Q> __device__ __forceinline__ void rot_lane(v2f* w, float g00, float g01,
                                                         float g10, float g11, int lane) {
    const int bit  = (lane >> Q) & 1;
    const float c1 = bit ? g11 : g00;   // own
    const float c0 = bit ? g10 : g01;   // partner
#pragma unroll
    for (int t = 0; t < 4; ++t) {
        v2f pw = sxv<(1 << Q)>(w[t]);
        w[t] = c1 * w[t] + c0 * pw;
    }
}
// rotation on wave bit QW (qubit 6+QW) via LDS exchange; one barrier (double-buffered by caller)
template<int QW> __device__ __forceinline__ void rot_wave(v2f* w, v2f* vbuf, int my, int wv,
                                                          float g00, float g01, float g10, float g11) {
    const int bit  = (wv >> QW) & 1;
    const float c1 = bit ? g11 : g00;
    const float c0 = bit ? g10 : g01;
#pragma unroll
    for (int t = 0; t < 4; ++t) vbuf[my + (t << 8)] = w[t];
    __syncthreads();
#pragma unroll
    for (int t = 0; t < 4; ++t) {
        v2f pw = vbuf[(my ^ (64 << QW)) + (t << 8)];
        w[t] = c1 * w[t] + c0 * pw;
    }
}
// rotation on component bit (qubit 8)
__device__ __forceinline__ void rot_comp(v2f* w, float g00, float g01, float g10, float g11) {
    v2f ca; ca.x = g00; ca.y = g11;
    v2f cb; cb.x = g01; cb.y = g10;
#pragma unroll
    for (int t = 0; t < 4; ++t) {
        v2f sw; sw.x = w[t].y; sw.y = w[t].x;
        w[t] = ca * w[t] + cb * sw;
    }
}
// rotation on reg bit B (qubit 9+B)
template<int B> __device__ __forceinline__ void rot_reg(v2f* w, float g00, float g01,
                                                        float g10, float g11) {
#pragma unroll
    for (int t = 0; t < 2; ++t) {
        const int j0 = ((t >> B) << (B + 1)) | (t & ((1 << B) - 1));
        const int j1 = j0 | (1 << B);
        v2f a0 = w[j0], a1 = w[j1];
        w[j0] = g00 * a0 + g01 * a1;
        w[j1] = g10 * a0 + g11 * a1;
    }
}
// ent ctrl lane bit Q, target lane bit Q+1 (Q<5)
template<int Q> __device__ __forceinline__ void ent_lane(v2f* w, float p, int lane) {
    const float pact = p * (float)((lane >> Q) & 1);
#pragma unroll
    for (int t = 0; t < 4; ++t) {
        v2f pw = sxv<(1 << (Q + 1))>(w[t]);
        w[t] = w[t] + pact * (pw - w[t]);
    }
}
// ent with target = wave bit QW, pact already includes ctrl-bit mask
template<int QW> __device__ __forceinline__ void ent_wave(v2f* w, v2f* vbuf, int my, float pact) {
#pragma unroll
    for (int t = 0; t < 4; ++t) vbuf[my + (t << 8)] = w[t];
    __syncthreads();
#pragma unroll
    for (int t = 0; t < 4; ++t) {
        v2f pw = vbuf[(my ^ (64 << QW)) + (t << 8)];
        w[t] = w[t] + pact * (pw - w[t]);
    }
}
// ent q7: ctrl wave bit1 (in pact), target comp
__device__ __forceinline__ void ent_comp(v2f* w, float pact) {
#pragma unroll
    for (int t = 0; t < 4; ++t) {
        v2f sw; sw.x = w[t].y; sw.y = w[t].x;
        w[t] = w[t] + pact * (sw - w[t]);
    }
}
// ent q8: ctrl comp==1 (y), target reg bit0: pairs (0,1),(2,3) on .y
__device__ __forceinline__ void ent_q8(v2f* w, float p) {
#pragma unroll
    for (int t = 0; t < 2; ++t) {
        const int j0 = 2 * t, j1 = 2 * t + 1;
        const float d = w[j1].y - w[j0].y;
        w[j0].y = fmaf(p, d, w[j0].y);
        w[j1].y = fmaf(-p, d, w[j1].y);
    }
}
// ent q9: ctrl reg bit0==1, target reg bit1: pair (1,3) full v2f
__device__ __forceinline__ void ent_q9(v2f* w, float p) {
    v2f d = w[3] - w[1];
    w[1] = w[1] + p * d;
    w[3] = w[3] - p * d;
}

// One NODE per 256-thread block (768 blocks, 3072 waves). 12 LDS barriers total.
__global__ __launch_bounds__(256) void circuit_kernel(
    const float* __restrict__ nf,     // [NB*NA, NF]
    const float* __restrict__ W1,     // [64,100]
    const float* __restrict__ b1,     // [64]
    const float* __restrict__ W2,     // [11,64]
    const float* __restrict__ b2,     // [11]
    const float* __restrict__ rot,    // [NL,NQ,3]
    const float* __restrict__ ent,    // [NL,NQ-1]
    const float* __restrict__ pool_w, // [11]
    float* __restrict__ Rpart)        // [NB*NA, S]
{
    __shared__ float xsh[64];
    __shared__ float part[4][64];
    __shared__ float fsh[NQ];
    __shared__ v2f xbuf[2][1024];     // double-buffered exchange, 2 x 8 KB

    const int tid  = threadIdx.x;
    const int lane = tid & 63;
    const int wv   = tid >> 6;
    const int node = blockIdx.x;
    const int a    = node % NA;

    // ---- feature MLP: 256 threads compute 64x64 dot products in 4 k-segments ----
    if (tid < 64) xsh[tid] = nf[node * NF + tid];
    __syncthreads();
    {
        const int row = lane, seg = wv;
        const float* wr = W1 + row * PADW + seg * 16;
        const float* xv = xsh + seg * 16;
        float acc = 0.0f;
#pragma unroll
        for (int j = 0; j < 16; ++j) acc = fmaf(wr[j], xv[j], acc);
        part[seg][row] = acc;
    }
    __syncthreads();
    if (tid < 64) {
        float h = b1[tid] + part[0][tid] + part[1][tid] + part[2][tid] + part[3][tid];
        h = fmaxf(h, 0.0f);
#pragma unroll
        for (int q = 0; q < NQ; ++q) {
            float t = h * W2[q * 64 + lane];
#pragma unroll
            for (int off = 32; off >= 1; off >>= 1) t += __shfl_xor(t, off, 64);
            if (lane == q) fsh[q] = tanhf(t + b2[q]);
        }
    }
    __syncthreads();

    // ---- per-wave (redundant) gate matrices: lane g<33 owns gate g ----
    const int qidx = lane < 11 ? lane : (lane < 22 ? lane - 11 : (lane < 33 ? lane - 22 : 0));
    const float fg = fsh[qidx];
    float m00 = 0.f, m01 = 0.f, m10 = 0.f, m11 = 0.f;
    if (lane < NL * NQ) {
        const float* r = rot + lane * 3;
        const float hx = 0.5f * r[0] * fg;
        const float hy = 0.5f * r[1] * fg;
        const float hz = 0.5f * r[2] * fg;
        const float cx = cosf(hx), sx = sinf(hx);
        const float cy = cosf(hy), sy = sinf(hy);
        const float cz = cosf(hz), sz = sinf(hz);
        m00 = cx * cy * cz; m01 = -sx * sy * sz;
        m10 = sx * sy * cz; m11 = cx * cy * sz;
    }
    float pent = 0.0f;
    if (lane < NL * (NQ - 1)) pent = sigmoidf_(ent[lane]);

    // ---- statevector: 8 states/thread, s = lane | wv<<6 | comp<<8 | t<<9 ----
    v2f w[4];
#pragma unroll
    for (int t = 0; t < 4; ++t) { w[t].x = 0.0f; w[t].y = 0.0f; }
    if (tid == 0) w[0].x = 1.0f;

    v2f* const B0 = xbuf[0];
    v2f* const B1 = xbuf[1];
    const int my = tid;               // lane + (wv<<6)

#define GC(G) const int gi = gb + (G); \
    const float g00 = rl_(m00, gi), g01 = rl_(m01, gi), g10 = rl_(m10, gi), g11 = rl_(m11, gi)
#define ROTL(Q) { GC(Q); rot_lane<Q>(w, g00, g01, g10, g11, lane); }
#define ENTL(Q) { const float p = rl_(pent, eb + (Q)); ent_lane<Q>(w, p, lane); }

    for (int l = 0; l < NL; ++l) {
        const int gb = l * NQ;
        const int eb = l * (NQ - 1);
        ROTL(0) ROTL(1) ROTL(2) ROTL(3) ROTL(4) ROTL(5)
        { GC(6); rot_wave<0>(w, B0, my, wv, g00, g01, g10, g11); }
        { GC(7); rot_wave<1>(w, B1, my, wv, g00, g01, g10, g11); }
        { GC(8); rot_comp(w, g00, g01, g10, g11); }
        { GC(9); rot_reg<0>(w, g00, g01, g10, g11); }
        { GC(10); rot_reg<1>(w, g00, g01, g10, g11); }
        ENTL(0) ENTL(1) ENTL(2) ENTL(3) ENTL(4)
        { const float p = rl_(pent, eb + 5); ent_wave<0>(w, B0, my, p * (float)((lane >> 5) & 1)); }
        { const float p = rl_(pent, eb + 6); ent_wave<1>(w, B1, my, p * (float)(wv & 1)); }
        { const float p = rl_(pent, eb + 7); ent_comp(w, p * (float)((wv >> 1) & 1)); }
        { const float p = rl_(pent, eb + 8); ent_q8(w, p); }
        { const float p = rl_(pent, eb + 9); ent_q9(w, p); }
    }

    // ---- weighted partial store (true state layout, coalesced per (comp,t)) ----
    const float wgt = sigmoidf_(pool_w[a % NQ]);
    float* Rb = Rpart + (size_t)node * S;
#pragma unroll
    for (int t = 0; t < 4; ++t) {
        Rb[tid + (t << 9)]       = wgt * w[t].x;
        Rb[tid + 256 + (t << 9)] = wgt * w[t].y;
    }
}

// One block per batch: sum 96 node partials, phase sums, 22->256->128->64 MLP.
__global__ __launch_bounds__(1024) void pool_mlp_kernel(
    const float* __restrict__ Rpart,  // [NB*NA, S]
    const float* __restrict__ msg,    // [NL,NQ,3]
    const float* __restrict__ Wo1, const float* __restrict__ bo1,
    const float* __restrict__ Wo2, const float* __restrict__ bo2,
    const float* __restrict__ Wo3, const float* __restrict__ bo3,
    float* __restrict__ out)          // [NB,64]
{
    __shared__ float Theta[NQ];
    __shared__ float red[3][16];
    __shared__ float rm_sh, im_sh;
    __shared__ float h1[256];
    __shared__ float h2[128];

    const int b   = blockIdx.x;
    const int tid = threadIdx.x;

    if (tid < NQ) {
        float t = 0.0f;
        for (int l = 0; l < NL; ++l)
#pragma unroll
            for (int c = 0; c < 3; ++c) t += msg[(l * NQ + tid) * 3 + c];
        Theta[tid] = t;
    }
    __syncthreads();

    float psq = 0.0f, pc = 0.0f, ps = 0.0f;
    const float* Pb = Rpart + (size_t)b * NA * S;
    for (int s = tid; s < S; s += 1024) {          // 2 iterations
        float R = 0.0f;
#pragma unroll 8
        for (int j = 0; j < NA; ++j) R += Pb[(size_t)j * S + s];
        float phi = 0.0f;
#pragma unroll
        for (int q = 0; q < NQ; ++q)
            if ((s >> q) & 1) phi += Theta[q];
        psq += R * R;
        pc  += R * cosf(phi);
        ps  += R * sinf(phi);
    }
#pragma unroll
    for (int off = 32; off >= 1; off >>= 1) {
        psq += __shfl_xor(psq, off, 64);
        pc  += __shfl_xor(pc,  off, 64);
        ps  += __shfl_xor(ps,  off, 64);
    }
    const int lane = tid & 63, wave = tid >> 6;
    if (lane == 0) { red[0][wave] = psq; red[1][wave] = pc; red[2][wave] = ps; }
    __syncthreads();
    if (tid == 0) {
        float sq = 0.f, sc = 0.f, ss = 0.f;
#pragma unroll
        for (int wv = 0; wv < 16; ++wv) { sq += red[0][wv]; sc += red[1][wv]; ss += red[2][wv]; }
        const float norm = fmaxf(sqrtf(sq), 1e-12f);
        rm_sh = sc / (float)S / norm;
        im_sh = ss / (float)S / norm;
    }
    __syncthreads();
    const float rm = rm_sh, im = im_sh;

    if (tid < 256) {
        float s1 = 0.0f, s2 = 0.0f;
        const float* wrow = Wo1 + tid * (2 * NQ);
#pragma unroll
        for (int k = 0; k < NQ; ++k)       s1 += wrow[k];
#pragma unroll
        for (int k = NQ; k < 2 * NQ; ++k)  s2 += wrow[k];
        h1[tid] = fmaxf(rm * s1 + im * s2 + bo1[tid], 0.0f);
    }
    __syncthreads();
    if (tid < 128) {
        float acc = bo2[tid];
        const float* wrow = Wo2 + tid * 256;
        for (int k = 0; k < 256; ++k) acc += h1[k] * wrow[k];
        h2[tid] = fmaxf(acc, 0.0f);
    }
    __syncthreads();
    if (tid < 64) {
        float acc = bo3[tid];
        const float* wrow = Wo3 + tid * 128;
        for (int k = 0; k < 128; ++k) acc += h2[k] * wrow[k];
        out[b * 64 + tid] = acc;
    }
}

extern "C" void kernel_launch(void* const* d_in, const int* in_sizes, int n_in,
                              void* d_out, int out_size, void* d_ws, size_t ws_size,
                              hipStream_t stream) {
    const float* nf     = (const float*)d_in[0];
    // d_in[1] = edge_indices (unused by the math)
    const float* W1     = (const float*)d_in[2];
    const float* b1     = (const float*)d_in[3];
    const float* W2     = (const float*)d_in[4];
    const float* b2     = (const float*)d_in[5];
    const float* rot    = (const float*)d_in[6];
    const float* ent    = (const float*)d_in[7];
    const float* msg    = (const float*)d_in[8];
    const float* pool_w = (const float*)d_in[9];
    const float* Wo1    = (const float*)d_in[10];
    const float* bo1    = (const float*)d_in[11];
    const float* Wo2    = (const float*)d_in[12];
    const float* bo2    = (const float*)d_in[13];
    const float* Wo3    = (const float*)d_in[14];
    const float* bo3    = (const float*)d_in[15];

    float* Rpart = (float*)d_ws;      // [NB*NA, S] per-node weighted partials

    circuit_kernel<<<dim3(NB * NA), dim3(256), 0, stream>>>(
        nf, W1, b1, W2, b2, rot, ent, pool_w, Rpart);

    pool_mlp_kernel<<<dim3(NB), dim3(1024), 0, stream>>>(
        Rpart, msg, Wo1, bo1, Wo2, bo2, Wo3, bo3, (float*)d_out);
}

// Round 6
// 118.028 us; speedup vs baseline: 1.0813x; 1.0813x over previous
//
#include <hip/hip_runtime.h>

#define NQ 11
#define NL 3
#define S  2048
#define NB 8
#define NA 96
#define NF 64
#define PADW 100
#define WPB 4            // waves (nodes) per block
#define PPB (NA / WPB)   // partial blocks per batch = 24

typedef float v2f __attribute__((ext_vector_type(2)));

__device__ __forceinline__ float sigmoidf_(float x) { return 1.0f / (1.0f + expf(-x)); }

// uniform broadcast from a given lane (SGPR path, no DS traffic) — verified r4/r5
__device__ __forceinline__ float rl_(float v, int srclane) {
    return __builtin_bit_cast(float, __builtin_amdgcn_readlane(__builtin_bit_cast(int, v), srclane));
}

// lane-xor shuffle: DPP for masks 1,2,8; ds_swizzle for 4,16; shfl for 32 — verified r4/r5
template<int M> __device__ __forceinline__ float sxf(float x) {
    if constexpr (M == 1)
        return __builtin_bit_cast(float, __builtin_amdgcn_mov_dpp(__builtin_bit_cast(int, x), 0xB1, 0xF, 0xF, true));
    else if constexpr (M == 2)
        return __builtin_bit_cast(float, __builtin_amdgcn_mov_dpp(__builtin_bit_cast(int, x), 0x4E, 0xF, 0xF, true));
    else if constexpr (M == 8)
        return __builtin_bit_cast(float, __builtin_amdgcn_mov_dpp(__builtin_bit_cast(int, x), 0x128, 0xF, 0xF, true));
    else if constexpr (M == 4)
        return __builtin_bit_cast(float, __builtin_amdgcn_ds_swizzle(__builtin_bit_cast(int, x), 0x101F));
    else if constexpr (M == 16)
        return __builtin_bit_cast(float, __builtin_amdgcn_ds_swizzle(__builtin_bit_cast(int, x), 0x401F));
    else
        return __shfl_xor(x, 32, 64);
}
template<int M> __device__ __forceinline__ v2f sxv(v2f w) {
    v2f r; r.x = sxf<M>(w.x); r.y = sxf<M>(w.y); return r;
}

// ---- gate primitives on packed statevector w[16]: state = ((2j+c)<<6)|lane ----
// (all verified correct in r4's fused kernel, absmax 0.0)
template<int Q> __device__ __forceinline__ void rot_lane(v2f* w, float g00, float g01,
                                                         float g10, float g11, int lane) {
    const int bit  = (lane >> Q) & 1;
    const float c1 = bit ? g11 : g00;   // own
    const float c0 = bit ? g10 : g01;   // partner
#pragma unroll
    for (int j = 0; j < 16; ++j) {
        v2f pw = sxv<(1 << Q)>(w[j]);
        w[j] = c1 * w[j] + c0 * pw;     // pk_mul + pk_fma
    }
}
__device__ __forceinline__ void rot_comp(v2f* w, float g00, float g01, float g10, float g11) {
    v2f ca; ca.x = g00; ca.y = g11;
    v2f cb; cb.x = g01; cb.y = g10;
#pragma unroll
    for (int j = 0; j < 16; ++j) {
        v2f sw; sw.x = w[j].y; sw.y = w[j].x;
        w[j] = ca * w[j] + cb * sw;
    }
}
template<int B> __device__ __forceinline__ void rot_reg(v2f* w, float g00, float g01,
                                                        float g10, float g11) {
#pragma unroll
    for (int t = 0; t < 8; ++t) {
        const int j0 = ((t >> B) << (B + 1)) | (t & ((1 << B) - 1));
        const int j1 = j0 | (1 << B);
        v2f a0 = w[j0], a1 = w[j1];
        w[j0] = g00 * a0 + g01 * a1;
        w[j1] = g10 * a0 + g11 * a1;
    }
}
template<int Q> __device__ __forceinline__ void ent_lane(v2f* w, float p, int lane) {
    const float pact = p * (float)((lane >> Q) & 1);
#pragma unroll
    for (int j = 0; j < 16; ++j) {
        v2f pw = sxv<(1 << (Q + 1))>(w[j]);
        w[j] = w[j] + pact * (pw - w[j]);
    }
}
__device__ __forceinline__ void ent_5(v2f* w, float p, int lane) {
    const float pact = p * (float)((lane >> 5) & 1);
#pragma unroll
    for (int j = 0; j < 16; ++j) {
        v2f sw; sw.x = w[j].y; sw.y = w[j].x;
        w[j] = w[j] + pact * (sw - w[j]);
    }
}
__device__ __forceinline__ void ent_6(v2f* w, float p) {
#pragma unroll
    for (int t = 0; t < 8; ++t) {
        const int j0 = 2 * t, j1 = 2 * t + 1;
        const float d = w[j1].y - w[j0].y;
        w[j0].y = fmaf(p, d, w[j0].y);
        w[j1].y = fmaf(-p, d, w[j1].y);
    }
}
template<int B> __device__ __forceinline__ void ent_reg(v2f* w, float p) {
#pragma unroll
    for (int t = 0; t < 4; ++t) {
        const int j0 = ((t >> B) << (B + 2)) | (1 << B) | (t & ((1 << B) - 1));
        const int j1 = j0 | (1 << (B + 1));
        v2f d = w[j1] - w[j0];
        w[j0] = w[j0] + p * d;
        w[j1] = w[j1] - p * d;
    }
}

// One WAVE per node (192 blocks x 256 thr). Block reduces its 4 nodes in LDS,
// stores ONE partial per block. No atomics, no fences, 3 barriers total.
__global__ __launch_bounds__(256) void circuit_kernel(
    const float* __restrict__ nf,     // [NB*NA, NF]
    const float* __restrict__ W1,     // [64,100]
    const float* __restrict__ b1,     // [64]
    const float* __restrict__ W2,     // [11,64]
    const float* __restrict__ b2,     // [11]
    const float* __restrict__ rot,    // [NL,NQ,3]
    const float* __restrict__ ent,    // [NL,NQ-1]
    const float* __restrict__ pool_w, // [11]
    float* __restrict__ Rpart)        // [PPB*NB, S]
{
    __shared__ float W1s[64 * 65];    // stride-65 pad: 2-way bank alias (free)
    __shared__ float xs[WPB][64];
    __shared__ float psum[WPB][S];

    const int tid  = threadIdx.x;
    const int lane = tid & 63;
    const int wave = tid >> 6;
    const int node = blockIdx.x * WPB + wave;
    const int a    = node % NA;

    // ---- stage W1[:,0:64] into padded LDS + node features ----
    {
        const int r  = tid >> 2;
        const int c0 = (tid & 3) << 4;
        const float4* src = reinterpret_cast<const float4*>(W1 + r * PADW + c0);
        float* dst = &W1s[r * 65 + c0];
#pragma unroll
        for (int j = 0; j < 4; ++j) {
            const float4 vv = src[j];
            dst[4 * j + 0] = vv.x; dst[4 * j + 1] = vv.y;
            dst[4 * j + 2] = vv.z; dst[4 * j + 3] = vv.w;
        }
        xs[wave][lane] = nf[blockIdx.x * WPB * NF + tid];
    }
    __syncthreads();

    // ---- h = relu(x @ W1[:, :64]^T + b1) ----
    float h = b1[lane];
    {
        const float* wrow = &W1s[lane * 65];
        const float* xv   = xs[wave];
#pragma unroll
        for (int k = 0; k < 64; ++k) h = fmaf(wrow[k], xv[k], h);
    }
    h = fmaxf(h, 0.0f);

    // ---- f[q] = tanh(b2[q] + h @ W2[q,:]) via wave butterfly; lane q keeps it ----
    float fscal = 0.0f;
#pragma unroll
    for (int q = 0; q < NQ; ++q) {
        float t = h * W2[q * 64 + lane];
#pragma unroll
        for (int off = 32; off >= 1; off >>= 1) t += __shfl_xor(t, off, 64);
        if (lane == q) fscal = tanhf(t + b2[q]);
    }

    // ---- lane g<33 computes gate g's 2x2 matrix; lane e<30 the ent p ----
    const int qidx = lane < 11 ? lane : (lane < 22 ? lane - 11 : (lane < 33 ? lane - 22 : 0));
    const float fg = __shfl(fscal, qidx, 64);
    float m00 = 0.f, m01 = 0.f, m10 = 0.f, m11 = 0.f;
    if (lane < NL * NQ) {
        const float* r = rot + lane * 3;
        const float hx = 0.5f * r[0] * fg;
        const float hy = 0.5f * r[1] * fg;
        const float hz = 0.5f * r[2] * fg;
        const float cx = cosf(hx), sx = sinf(hx);
        const float cy = cosf(hy), sy = sinf(hy);
        const float cz = cosf(hz), sz = sinf(hz);
        m00 = cx * cy * cz; m01 = -sx * sy * sz;
        m10 = sx * sy * cz; m11 = cx * cy * sz;
    }
    float pent = 0.0f;
    if (lane < NL * (NQ - 1)) pent = sigmoidf_(ent[lane]);

    // ---- packed register statevector ----
    v2f w[16];
#pragma unroll
    for (int j = 0; j < 16; ++j) { w[j].x = 0.0f; w[j].y = 0.0f; }
    if (lane == 0) w[0].x = 1.0f;

#define GC(G) const int gi = gb + (G); \
    const float g00 = rl_(m00, gi), g01 = rl_(m01, gi), g10 = rl_(m10, gi), g11 = rl_(m11, gi)
#define ROTL(Q) { GC(Q); rot_lane<Q>(w, g00, g01, g10, g11, lane); }
#define ROTR(B) { GC((B) + 7); rot_reg<B>(w, g00, g01, g10, g11); }
#define ENTL(Q) { const float p = rl_(pent, eb + (Q)); ent_lane<Q>(w, p, lane); }

    for (int l = 0; l < NL; ++l) {
        const int gb = l * NQ;
        const int eb = l * (NQ - 1);
        ROTL(0) ROTL(1) ROTL(2) ROTL(3) ROTL(4) ROTL(5)
        { GC(6); rot_comp(w, g00, g01, g10, g11); }
        ROTR(0) ROTR(1) ROTR(2) ROTR(3)
        ENTL(0) ENTL(1) ENTL(2) ENTL(3) ENTL(4)
        { const float p = rl_(pent, eb + 5); ent_5(w, p, lane); }
        { const float p = rl_(pent, eb + 6); ent_6(w, p); }
        { const float p = rl_(pent, eb + 7); ent_reg<0>(w, p); }
        { const float p = rl_(pent, eb + 8); ent_reg<1>(w, p); }
        { const float p = rl_(pent, eb + 9); ent_reg<2>(w, p); }
    }

    // ---- weighted write into LDS, block reduction, ONE partial store ----
    const float wgt = sigmoidf_(pool_w[a % NQ]);
#pragma unroll
    for (int j = 0; j < 16; ++j) {
        psum[wave][((2 * j + 0) << 6) | lane] = wgt * w[j].x;
        psum[wave][((2 * j + 1) << 6) | lane] = wgt * w[j].y;
    }
    __syncthreads();
    {
        float* Rb = Rpart + (size_t)blockIdx.x * S;
        for (int s = tid; s < S; s += 256)
            Rb[s] = psum[0][s] + psum[1][s] + psum[2][s] + psum[3][s];
    }
}

// One block per batch (512 thr): sum 24 partials with float4 loads,
// phase sums, 22->256->128->64 MLP.
__global__ __launch_bounds__(512) void pool_mlp_kernel(
    const float* __restrict__ Rpart,  // [NB*PPB, S]
    const float* __restrict__ msg,    // [NL,NQ,3]
    const float* __restrict__ Wo1, const float* __restrict__ bo1,
    const float* __restrict__ Wo2, const float* __restrict__ bo2,
    const float* __restrict__ Wo3, const float* __restrict__ bo3,
    float* __restrict__ out)          // [NB,64]
{
    __shared__ float Theta[NQ];
    __shared__ float red[3][8];
    __shared__ float rm_sh, im_sh;
    __shared__ float h1[256];
    __shared__ float h2[128];

    const int b   = blockIdx.x;
    const int tid = threadIdx.x;

    if (tid < NQ) {
        float t = 0.0f;
        for (int l = 0; l < NL; ++l)
#pragma unroll
            for (int c = 0; c < 3; ++c) t += msg[(l * NQ + tid) * 3 + c];
        Theta[tid] = t;
    }
    __syncthreads();

    // each thread owns one float4 (4 consecutive states): 512 * 4 = 2048
    float psq = 0.0f, pc = 0.0f, ps = 0.0f;
    {
        const float4* Pb = reinterpret_cast<const float4*>(Rpart + (size_t)b * PPB * S);
        float4 R; R.x = 0.f; R.y = 0.f; R.z = 0.f; R.w = 0.f;
#pragma unroll 6
        for (int j = 0; j < PPB; ++j) {
            const float4 v = Pb[j * (S / 4) + tid];
            R.x += v.x; R.y += v.y; R.z += v.z; R.w += v.w;
        }
        const int s0 = tid * 4;
        float phiH = 0.0f;
#pragma unroll
        for (int q = 2; q < NQ; ++q)
            if ((s0 >> q) & 1) phiH += Theta[q];
        const float t0 = Theta[0], t1 = Theta[1];
        const float ph0 = phiH, ph1 = phiH + t0, ph2 = phiH + t1, ph3 = phiH + t0 + t1;
        psq = R.x * R.x + R.y * R.y + R.z * R.z + R.w * R.w;
        pc  = R.x * cosf(ph0) + R.y * cosf(ph1) + R.z * cosf(ph2) + R.w * cosf(ph3);
        ps  = R.x * sinf(ph0) + R.y * sinf(ph1) + R.z * sinf(ph2) + R.w * sinf(ph3);
    }
#pragma unroll
    for (int off = 32; off >= 1; off >>= 1) {
        psq += __shfl_xor(psq, off, 64);
        pc  += __shfl_xor(pc,  off, 64);
        ps  += __shfl_xor(ps,  off, 64);
    }
    const int lane = tid & 63, wave = tid >> 6;
    if (lane == 0) { red[0][wave] = psq; red[1][wave] = pc; red[2][wave] = ps; }
    __syncthreads();
    if (tid == 0) {
        float sq = 0.f, sc = 0.f, ss = 0.f;
#pragma unroll
        for (int wv = 0; wv < 8; ++wv) { sq += red[0][wv]; sc += red[1][wv]; ss += red[2][wv]; }
        const float norm = fmaxf(sqrtf(sq), 1e-12f);
        rm_sh = sc / (float)S / norm;
        im_sh = ss / (float)S / norm;
    }
    __syncthreads();
    const float rm = rm_sh, im = im_sh;

    // h1[j] = relu(rm * sum(Wo1[j,0:11]) + im * sum(Wo1[j,11:22]) + bo1[j])
    if (tid < 256) {
        float s1 = 0.0f, s2 = 0.0f;
        const float* wrow = Wo1 + tid * (2 * NQ);
#pragma unroll
        for (int k = 0; k < NQ; ++k)       s1 += wrow[k];
#pragma unroll
        for (int k = NQ; k < 2 * NQ; ++k)  s2 += wrow[k];
        h1[tid] = fmaxf(rm * s1 + im * s2 + bo1[tid], 0.0f);
    }
    __syncthreads();
    if (tid < 128) {
        float acc = bo2[tid];
        const float* wrow = Wo2 + tid * 256;
        for (int k = 0; k < 256; ++k) acc += h1[k] * wrow[k];
        h2[tid] = fmaxf(acc, 0.0f);
    }
    __syncthreads();
    if (tid < 64) {
        float acc = bo3[tid];
        const float* wrow = Wo3 + tid * 128;
        for (int k = 0; k < 128; ++k) acc += h2[k] * wrow[k];
        out[b * 64 + tid] = acc;
    }
}

extern "C" void kernel_launch(void* const* d_in, const int* in_sizes, int n_in,
                              void* d_out, int out_size, void* d_ws, size_t ws_size,
                              hipStream_t stream) {
    const float* nf     = (const float*)d_in[0];
    // d_in[1] = edge_indices (unused by the math)
    const float* W1     = (const float*)d_in[2];
    const float* b1     = (const float*)d_in[3];
    const float* W2     = (const float*)d_in[4];
    const float* b2     = (const float*)d_in[5];
    const float* rot    = (const float*)d_in[6];
    const float* ent    = (const float*)d_in[7];
    const float* msg    = (const float*)d_in[8];
    const float* pool_w = (const float*)d_in[9];
    const float* Wo1    = (const float*)d_in[10];
    const float* bo1    = (const float*)d_in[11];
    const float* Wo2    = (const float*)d_in[12];
    const float* bo2    = (const float*)d_in[13];
    const float* Wo3    = (const float*)d_in[14];
    const float* bo3    = (const float*)d_in[15];

    float* Rpart = (float*)d_ws;     // [NB*PPB, S] block partials (plain stores)

    circuit_kernel<<<dim3(NB * NA / WPB), dim3(256), 0, stream>>>(
        nf, W1, b1, W2, b2, rot, ent, pool_w, Rpart);

    pool_mlp_kernel<<<dim3(NB), dim3(512), 0, stream>>>(
        Rpart, msg, Wo1, bo1, Wo2, bo2, Wo3, bo3, (float*)d_out);
}